// Round 1
// baseline (2143.708 us; speedup 1.0000x reference)
//
#include <hip/hip_runtime.h>
#include <math.h>

// Problem constants (fixed by setup_inputs)
#define BB 4
#define HH 128
#define DD 512
#define WW 512
#define GG 72
#define PP 65536
#define CHUNK 256
#define NCHUNK (PP / CHUNK)          // 256
#define HDW (HH * DD * WW)           // 33,554,432

// ---------------------------------------------------------------------------
// Kernel 1: trilinear density for all 4 batches + per-chunk sums + step-dist
// grid = (NCHUNK, GG), block = 256, 1 point per thread.
// density is written into d_out (same element count as the final output).
// ---------------------------------------------------------------------------
__global__ __launch_bounds__(256) void k_density(
    const float* __restrict__ ct,       // [B, H, D, W]
    const float* __restrict__ coords,   // [G, P, 3]
    float* __restrict__ density,        // [B*G, P]  (aliases d_out)
    float* __restrict__ chunk_sums,     // [B*G, NCHUNK]
    float* __restrict__ step_accum)     // [G]
{
    const int chunk = blockIdx.x;
    const int g     = blockIdx.y;
    const int t     = threadIdx.x;
    const int p     = chunk * CHUNK + t;

    __shared__ float cbuf[(CHUNK + 1) * 3];   // 257 coords (for p+1 diff)
    __shared__ float wsum[4][5];

    // cooperative coord load (coalesced, contiguous)
    const int nload = (chunk == NCHUNK - 1) ? CHUNK * 3 : (CHUNK + 1) * 3;
    const float* src = coords + ((size_t)g * PP + (size_t)chunk * CHUNK) * 3;
    for (int i = t; i < nload; i += CHUNK) cbuf[i] = src[i];
    __syncthreads();

    const float cx = cbuf[3 * t + 0];
    const float cy = cbuf[3 * t + 1];
    const float cz = cbuf[3 * t + 2];

    // step distance (raw coords, matching the reference)
    float dist = 0.0f;
    if (p < PP - 1) {
        const int nt = 3 * (t + 1);
        const float dx = cbuf[nt + 0] - cx;
        const float dy = cbuf[nt + 1] - cy;
        const float dz = cbuf[nt + 2] - cz;
        dist = sqrtf(dx * dx + dy * dy + dz * dz);
    }

    // clamp + corner indices (reference semantics)
    const float x = fminf(fmaxf(cx, 0.0f), (float)(WW - 1));
    const float y = fminf(fmaxf(cy, 0.0f), (float)(DD - 1));
    const float z = fminf(fmaxf(cz, 0.0f), (float)(HH - 1));
    const int x0 = (int)floorf(x);
    const int y0 = (int)floorf(y);
    const int z0 = (int)floorf(z);
    const int x1 = min(x0 + 1, WW - 1);
    const int y1 = min(y0 + 1, DD - 1);
    const int z1 = min(z0 + 1, HH - 1);
    const float xd = x - (float)x0;
    const float yd = y - (float)y0;
    const float zd = z - (float)z0;

    const int b00 = (z0 * DD + y0) * WW;
    const int b01 = (z0 * DD + y1) * WW;
    const int b10 = (z1 * DD + y0) * WW;
    const int b11 = (z1 * DD + y1) * WW;
    const int i000 = b00 + x0, i001 = b00 + x1;
    const int i010 = b01 + x0, i011 = b01 + x1;
    const int i100 = b10 + x0, i101 = b10 + x1;
    const int i110 = b11 + x0, i111 = b11 + x1;

    float dens[BB];
#pragma unroll
    for (int b = 0; b < BB; ++b) {
        const float* v = ct + (size_t)b * HDW;
        const float c000 = v[i000], c001 = v[i001];
        const float c010 = v[i010], c011 = v[i011];
        const float c100 = v[i100], c101 = v[i101];
        const float c110 = v[i110], c111 = v[i111];
        const float c00 = c000 * (1.0f - xd) + c001 * xd;
        const float c01 = c010 * (1.0f - xd) + c011 * xd;
        const float c10 = c100 * (1.0f - xd) + c101 * xd;
        const float c11 = c110 * (1.0f - xd) + c111 * xd;
        const float c0  = c00 * (1.0f - yd) + c01 * yd;
        const float c1  = c10 * (1.0f - yd) + c11 * yd;
        dens[b] = c0 * (1.0f - zd) + c1 * zd;
        density[((size_t)(b * GG + g)) * PP + p] = dens[b];
    }

    // block reduction: 4 density sums + step-distance sum
    const int lane = t & 63;
    const int wid  = t >> 6;
    float r0 = dens[0], r1 = dens[1], r2 = dens[2], r3 = dens[3], rd = dist;
#pragma unroll
    for (int off = 32; off > 0; off >>= 1) {
        r0 += __shfl_xor(r0, off);
        r1 += __shfl_xor(r1, off);
        r2 += __shfl_xor(r2, off);
        r3 += __shfl_xor(r3, off);
        rd += __shfl_xor(rd, off);
    }
    if (lane == 0) {
        wsum[wid][0] = r0; wsum[wid][1] = r1; wsum[wid][2] = r2;
        wsum[wid][3] = r3; wsum[wid][4] = rd;
    }
    __syncthreads();
    if (t == 0) {
        float s0 = 0, s1 = 0, s2 = 0, s3 = 0, sd = 0;
#pragma unroll
        for (int w = 0; w < 4; ++w) {
            s0 += wsum[w][0]; s1 += wsum[w][1]; s2 += wsum[w][2];
            s3 += wsum[w][3]; sd += wsum[w][4];
        }
        chunk_sums[((size_t)(0 * GG + g)) * NCHUNK + chunk] = s0;
        chunk_sums[((size_t)(1 * GG + g)) * NCHUNK + chunk] = s1;
        chunk_sums[((size_t)(2 * GG + g)) * NCHUNK + chunk] = s2;
        chunk_sums[((size_t)(3 * GG + g)) * NCHUNK + chunk] = s3;
        atomicAdd(&step_accum[g], sd);
    }
}

// ---------------------------------------------------------------------------
// Kernel 2: in-place exclusive scan of chunk sums per row. grid = B*G, blk=256
// ---------------------------------------------------------------------------
__global__ __launch_bounds__(256) void k_scan_chunks(float* __restrict__ cs)
{
    const int row = blockIdx.x;      // b*G + g
    const int t   = threadIdx.x;
    const int lane = t & 63;
    const int wid  = t >> 6;

    float v = cs[(size_t)row * NCHUNK + t];
    const float own = v;
#pragma unroll
    for (int d = 1; d < 64; d <<= 1) {
        const float n = __shfl_up(v, d);
        if (lane >= d) v += n;
    }
    __shared__ float ws[4];
    if (lane == 63) ws[wid] = v;
    __syncthreads();
    float prefix = 0.0f;
    for (int w = 0; w < wid; ++w) prefix += ws[w];
    cs[(size_t)row * NCHUNK + t] = prefix + v - own;   // exclusive
}

// ---------------------------------------------------------------------------
// Kernel 3: final scan + scale, in place over d_out. grid = (NCHUNK, GG)
// ---------------------------------------------------------------------------
__global__ __launch_bounds__(256) void k_output(
    float* __restrict__ out,                 // in: density, out: result
    const float* __restrict__ cs,            // exclusive chunk offsets
    const float* __restrict__ step_accum)    // [G]
{
    const int chunk = blockIdx.x;
    const int g     = blockIdx.y;
    const int t     = threadIdx.x;
    const int p     = chunk * CHUNK + t;
    const int lane  = t & 63;
    const int wid   = t >> 6;

    const float step = step_accum[g] * (2.0f / (float)(PP - 1));

    float d[BB], v[BB];
#pragma unroll
    for (int b = 0; b < BB; ++b) {
        d[b] = out[((size_t)(b * GG + g)) * PP + p];
        v[b] = d[b];
    }

    // 4 simultaneous inclusive wave scans
#pragma unroll
    for (int dd = 1; dd < 64; dd <<= 1) {
#pragma unroll
        for (int b = 0; b < BB; ++b) {
            const float n = __shfl_up(v[b], dd);
            if (lane >= dd) v[b] += n;
        }
    }
    __shared__ float ws[4][BB];
    if (lane == 63) {
#pragma unroll
        for (int b = 0; b < BB; ++b) ws[wid][b] = v[b];
    }
    __syncthreads();

#pragma unroll
    for (int b = 0; b < BB; ++b) {
        float prefix = 0.0f;
        for (int w = 0; w < wid; ++w) prefix += ws[w][b];
        const float excl = cs[((size_t)(b * GG + g)) * NCHUNK + chunk];
        const float incl = excl + prefix + v[b];
        out[((size_t)(b * GG + g)) * PP + p] = step * (incl + 0.5f * d[b]);
    }
}

// ---------------------------------------------------------------------------
extern "C" void kernel_launch(void* const* d_in, const int* in_sizes, int n_in,
                              void* d_out, int out_size, void* d_ws, size_t ws_size,
                              hipStream_t stream)
{
    const float* ct     = (const float*)d_in[0];
    const float* coords = (const float*)d_in[1];
    float* out = (float*)d_out;

    float* chunk_sums = (float*)d_ws;                       // B*G*NCHUNK floats
    float* step_accum = chunk_sums + (size_t)BB * GG * NCHUNK;  // G floats

    hipMemsetAsync(step_accum, 0, GG * sizeof(float), stream);

    k_density<<<dim3(NCHUNK, GG), 256, 0, stream>>>(ct, coords, out, chunk_sums, step_accum);
    k_scan_chunks<<<BB * GG, 256, 0, stream>>>(chunk_sums);
    k_output<<<dim3(NCHUNK, GG), 256, 0, stream>>>(out, chunk_sums, step_accum);
}

// Round 2
// 1174.638 us; speedup vs baseline: 1.8250x; 1.8250x over previous
//
#include <hip/hip_runtime.h>
#include <math.h>

// Problem constants (fixed by setup_inputs)
#define BB 4
#define HH 128
#define DD 512
#define WW 512
#define GG 72
#define PP 65536
#define CHUNK 256
#define NCHUNK (PP / CHUNK)          // 256
#define HDW (HH * DD * WW)           // 33,554,432

typedef _Float16 half4 __attribute__((ext_vector_type(4)));
typedef _Float16 half8 __attribute__((ext_vector_type(8)));

// ---------------------------------------------------------------------------
// Transpose + quantize: ct [B,H,D,W] fp32  ->  tv [H,D,W,B] fp16
// Each thread handles 4 consecutive voxels: 4x float4 reads, 2x 16B writes.
// ---------------------------------------------------------------------------
__global__ __launch_bounds__(256) void k_transpose(
    const float* __restrict__ ct, _Float16* __restrict__ tv)
{
    const size_t i = ((size_t)blockIdx.x * 256 + threadIdx.x) * 4;  // voxel idx
    const float4 a = *(const float4*)(ct + (size_t)0 * HDW + i);
    const float4 b = *(const float4*)(ct + (size_t)1 * HDW + i);
    const float4 c = *(const float4*)(ct + (size_t)2 * HDW + i);
    const float4 d = *(const float4*)(ct + (size_t)3 * HDW + i);
    half8 o0, o1;
    o0[0] = (_Float16)a.x; o0[1] = (_Float16)b.x; o0[2] = (_Float16)c.x; o0[3] = (_Float16)d.x;
    o0[4] = (_Float16)a.y; o0[5] = (_Float16)b.y; o0[6] = (_Float16)c.y; o0[7] = (_Float16)d.y;
    o1[0] = (_Float16)a.z; o1[1] = (_Float16)b.z; o1[2] = (_Float16)c.z; o1[3] = (_Float16)d.z;
    o1[4] = (_Float16)a.w; o1[5] = (_Float16)b.w; o1[6] = (_Float16)c.w; o1[7] = (_Float16)d.w;
    *(half8*)(tv + i * 4)     = o0;
    *(half8*)(tv + i * 4 + 8) = o1;
}

// ---------------------------------------------------------------------------
// Shared epilogue for density kernels: block reduction of 4 chunk sums + dist
// ---------------------------------------------------------------------------
__device__ __forceinline__ void density_reduce(
    const float dens[BB], float dist, int g, int chunk, int t,
    float* __restrict__ chunk_sums, float* __restrict__ step_accum)
{
    __shared__ float wsum[4][5];
    const int lane = t & 63;
    const int wid  = t >> 6;
    float r0 = dens[0], r1 = dens[1], r2 = dens[2], r3 = dens[3], rd = dist;
#pragma unroll
    for (int off = 32; off > 0; off >>= 1) {
        r0 += __shfl_xor(r0, off);
        r1 += __shfl_xor(r1, off);
        r2 += __shfl_xor(r2, off);
        r3 += __shfl_xor(r3, off);
        rd += __shfl_xor(rd, off);
    }
    if (lane == 0) {
        wsum[wid][0] = r0; wsum[wid][1] = r1; wsum[wid][2] = r2;
        wsum[wid][3] = r3; wsum[wid][4] = rd;
    }
    __syncthreads();
    if (t == 0) {
        float s0 = 0, s1 = 0, s2 = 0, s3 = 0, sd = 0;
#pragma unroll
        for (int w = 0; w < 4; ++w) {
            s0 += wsum[w][0]; s1 += wsum[w][1]; s2 += wsum[w][2];
            s3 += wsum[w][3]; sd += wsum[w][4];
        }
        chunk_sums[((size_t)(0 * GG + g)) * NCHUNK + chunk] = s0;
        chunk_sums[((size_t)(1 * GG + g)) * NCHUNK + chunk] = s1;
        chunk_sums[((size_t)(2 * GG + g)) * NCHUNK + chunk] = s2;
        chunk_sums[((size_t)(3 * GG + g)) * NCHUNK + chunk] = s3;
        atomicAdd(&step_accum[g], sd);
    }
}

// Coord staging + per-thread setup, shared by both density kernels.
struct PointSetup {
    int i000, i001, i010, i011, i100, i101, i110, i111;
    float xd, yd, zd, dist;
};

__device__ __forceinline__ PointSetup point_setup(
    const float* __restrict__ coords, int g, int chunk, int t, int p)
{
    __shared__ float cbuf[(CHUNK + 1) * 3];
    const int nload = (chunk == NCHUNK - 1) ? CHUNK * 3 : (CHUNK + 1) * 3;
    const float* src = coords + ((size_t)g * PP + (size_t)chunk * CHUNK) * 3;
    for (int i = t; i < nload; i += CHUNK) cbuf[i] = src[i];
    __syncthreads();

    const float cx = cbuf[3 * t + 0];
    const float cy = cbuf[3 * t + 1];
    const float cz = cbuf[3 * t + 2];

    PointSetup s;
    s.dist = 0.0f;
    if (p < PP - 1) {
        const int nt = 3 * (t + 1);
        const float dx = cbuf[nt + 0] - cx;
        const float dy = cbuf[nt + 1] - cy;
        const float dz = cbuf[nt + 2] - cz;
        s.dist = sqrtf(dx * dx + dy * dy + dz * dz);
    }

    const float x = fminf(fmaxf(cx, 0.0f), (float)(WW - 1));
    const float y = fminf(fmaxf(cy, 0.0f), (float)(DD - 1));
    const float z = fminf(fmaxf(cz, 0.0f), (float)(HH - 1));
    const int x0 = (int)floorf(x);
    const int y0 = (int)floorf(y);
    const int z0 = (int)floorf(z);
    const int x1 = min(x0 + 1, WW - 1);
    const int y1 = min(y0 + 1, DD - 1);
    const int z1 = min(z0 + 1, HH - 1);
    s.xd = x - (float)x0;
    s.yd = y - (float)y0;
    s.zd = z - (float)z0;

    const int b00 = (z0 * DD + y0) * WW;
    const int b01 = (z0 * DD + y1) * WW;
    const int b10 = (z1 * DD + y0) * WW;
    const int b11 = (z1 * DD + y1) * WW;
    s.i000 = b00 + x0; s.i001 = b00 + x1;
    s.i010 = b01 + x0; s.i011 = b01 + x1;
    s.i100 = b10 + x0; s.i101 = b10 + x1;
    s.i110 = b11 + x0; s.i111 = b11 + x1;
    return s;
}

// ---------------------------------------------------------------------------
// Fast density kernel: gathers from fp16 batch-interleaved volume.
// grid = (NCHUNK, GG), block = 256, 1 point per thread.
// ---------------------------------------------------------------------------
__global__ __launch_bounds__(256) void k_density_h(
    const _Float16* __restrict__ tv,    // [H, D, W, B] fp16
    const float* __restrict__ coords,   // [G, P, 3]
    float* __restrict__ density,        // [B*G, P]  (aliases d_out)
    float* __restrict__ chunk_sums,     // [B*G, NCHUNK]
    float* __restrict__ step_accum)     // [G]
{
    const int chunk = blockIdx.x;
    const int g     = blockIdx.y;
    const int t     = threadIdx.x;
    const int p     = chunk * CHUNK + t;

    const PointSetup s = point_setup(coords, g, chunk, t, p);

    // 8 independent 8-byte loads: all 4 batches per corner.
    const half4 a000 = *(const half4*)(tv + (size_t)s.i000 * 4);
    const half4 a001 = *(const half4*)(tv + (size_t)s.i001 * 4);
    const half4 a010 = *(const half4*)(tv + (size_t)s.i010 * 4);
    const half4 a011 = *(const half4*)(tv + (size_t)s.i011 * 4);
    const half4 a100 = *(const half4*)(tv + (size_t)s.i100 * 4);
    const half4 a101 = *(const half4*)(tv + (size_t)s.i101 * 4);
    const half4 a110 = *(const half4*)(tv + (size_t)s.i110 * 4);
    const half4 a111 = *(const half4*)(tv + (size_t)s.i111 * 4);

    float dens[BB];
#pragma unroll
    for (int b = 0; b < BB; ++b) {
        const float c000 = (float)a000[b], c001 = (float)a001[b];
        const float c010 = (float)a010[b], c011 = (float)a011[b];
        const float c100 = (float)a100[b], c101 = (float)a101[b];
        const float c110 = (float)a110[b], c111 = (float)a111[b];
        const float c00 = c000 * (1.0f - s.xd) + c001 * s.xd;
        const float c01 = c010 * (1.0f - s.xd) + c011 * s.xd;
        const float c10 = c100 * (1.0f - s.xd) + c101 * s.xd;
        const float c11 = c110 * (1.0f - s.xd) + c111 * s.xd;
        const float c0  = c00 * (1.0f - s.yd) + c01 * s.yd;
        const float c1  = c10 * (1.0f - s.yd) + c11 * s.yd;
        dens[b] = c0 * (1.0f - s.zd) + c1 * s.zd;
        density[((size_t)(b * GG + g)) * PP + p] = dens[b];
    }

    density_reduce(dens, s.dist, g, chunk, t, chunk_sums, step_accum);
}

// ---------------------------------------------------------------------------
// Fallback density kernel (fp32 direct gather) — used if ws too small.
// ---------------------------------------------------------------------------
__global__ __launch_bounds__(256) void k_density(
    const float* __restrict__ ct,
    const float* __restrict__ coords,
    float* __restrict__ density,
    float* __restrict__ chunk_sums,
    float* __restrict__ step_accum)
{
    const int chunk = blockIdx.x;
    const int g     = blockIdx.y;
    const int t     = threadIdx.x;
    const int p     = chunk * CHUNK + t;

    const PointSetup s = point_setup(coords, g, chunk, t, p);

    float dens[BB];
#pragma unroll
    for (int b = 0; b < BB; ++b) {
        const float* v = ct + (size_t)b * HDW;
        const float c000 = v[s.i000], c001 = v[s.i001];
        const float c010 = v[s.i010], c011 = v[s.i011];
        const float c100 = v[s.i100], c101 = v[s.i101];
        const float c110 = v[s.i110], c111 = v[s.i111];
        const float c00 = c000 * (1.0f - s.xd) + c001 * s.xd;
        const float c01 = c010 * (1.0f - s.xd) + c011 * s.xd;
        const float c10 = c100 * (1.0f - s.xd) + c101 * s.xd;
        const float c11 = c110 * (1.0f - s.xd) + c111 * s.xd;
        const float c0  = c00 * (1.0f - s.yd) + c01 * s.yd;
        const float c1  = c10 * (1.0f - s.yd) + c11 * s.yd;
        dens[b] = c0 * (1.0f - s.zd) + c1 * s.zd;
        density[((size_t)(b * GG + g)) * PP + p] = dens[b];
    }

    density_reduce(dens, s.dist, g, chunk, t, chunk_sums, step_accum);
}

// ---------------------------------------------------------------------------
// Kernel 2: in-place exclusive scan of chunk sums per row. grid = B*G, blk=256
// ---------------------------------------------------------------------------
__global__ __launch_bounds__(256) void k_scan_chunks(float* __restrict__ cs)
{
    const int row = blockIdx.x;      // b*G + g
    const int t   = threadIdx.x;
    const int lane = t & 63;
    const int wid  = t >> 6;

    float v = cs[(size_t)row * NCHUNK + t];
    const float own = v;
#pragma unroll
    for (int d = 1; d < 64; d <<= 1) {
        const float n = __shfl_up(v, d);
        if (lane >= d) v += n;
    }
    __shared__ float ws[4];
    if (lane == 63) ws[wid] = v;
    __syncthreads();
    float prefix = 0.0f;
    for (int w = 0; w < wid; ++w) prefix += ws[w];
    cs[(size_t)row * NCHUNK + t] = prefix + v - own;   // exclusive
}

// ---------------------------------------------------------------------------
// Kernel 3: final scan + scale, in place over d_out. grid = (NCHUNK, GG)
// ---------------------------------------------------------------------------
__global__ __launch_bounds__(256) void k_output(
    float* __restrict__ out,
    const float* __restrict__ cs,
    const float* __restrict__ step_accum)
{
    const int chunk = blockIdx.x;
    const int g     = blockIdx.y;
    const int t     = threadIdx.x;
    const int p     = chunk * CHUNK + t;
    const int lane  = t & 63;
    const int wid   = t >> 6;

    const float step = step_accum[g] * (2.0f / (float)(PP - 1));

    float d[BB], v[BB];
#pragma unroll
    for (int b = 0; b < BB; ++b) {
        d[b] = out[((size_t)(b * GG + g)) * PP + p];
        v[b] = d[b];
    }

#pragma unroll
    for (int dd = 1; dd < 64; dd <<= 1) {
#pragma unroll
        for (int b = 0; b < BB; ++b) {
            const float n = __shfl_up(v[b], dd);
            if (lane >= dd) v[b] += n;
        }
    }
    __shared__ float ws[4][BB];
    if (lane == 63) {
#pragma unroll
        for (int b = 0; b < BB; ++b) ws[wid][b] = v[b];
    }
    __syncthreads();

#pragma unroll
    for (int b = 0; b < BB; ++b) {
        float prefix = 0.0f;
        for (int w = 0; w < wid; ++w) prefix += ws[w][b];
        const float excl = cs[((size_t)(b * GG + g)) * NCHUNK + chunk];
        const float incl = excl + prefix + v[b];
        out[((size_t)(b * GG + g)) * PP + p] = step * (incl + 0.5f * d[b]);
    }
}

// ---------------------------------------------------------------------------
extern "C" void kernel_launch(void* const* d_in, const int* in_sizes, int n_in,
                              void* d_out, int out_size, void* d_ws, size_t ws_size,
                              hipStream_t stream)
{
    const float* ct     = (const float*)d_in[0];
    const float* coords = (const float*)d_in[1];
    float* out = (float*)d_out;

    const size_t volBytes = (size_t)HDW * BB * sizeof(_Float16);        // 256 MiB
    const size_t csCount  = (size_t)BB * GG * NCHUNK;
    const size_t needed   = volBytes + (csCount + GG) * sizeof(float);

    if (ws_size >= needed) {
        _Float16* tv       = (_Float16*)d_ws;
        float* chunk_sums  = (float*)((char*)d_ws + volBytes);
        float* step_accum  = chunk_sums + csCount;

        hipMemsetAsync(step_accum, 0, GG * sizeof(float), stream);
        k_transpose<<<HDW / (256 * 4), 256, 0, stream>>>(ct, tv);
        k_density_h<<<dim3(NCHUNK, GG), 256, 0, stream>>>(tv, coords, out, chunk_sums, step_accum);
        k_scan_chunks<<<BB * GG, 256, 0, stream>>>(chunk_sums);
        k_output<<<dim3(NCHUNK, GG), 256, 0, stream>>>(out, chunk_sums, step_accum);
    } else {
        float* chunk_sums  = (float*)d_ws;
        float* step_accum  = chunk_sums + csCount;

        hipMemsetAsync(step_accum, 0, GG * sizeof(float), stream);
        k_density<<<dim3(NCHUNK, GG), 256, 0, stream>>>(ct, coords, out, chunk_sums, step_accum);
        k_scan_chunks<<<BB * GG, 256, 0, stream>>>(chunk_sums);
        k_output<<<dim3(NCHUNK, GG), 256, 0, stream>>>(out, chunk_sums, step_accum);
    }
}